// Round 3
// baseline (162.318 us; speedup 1.0000x reference)
//
#include <hip/hip_runtime.h>

#define B_ 32
#define T_ 2048
#define C_ 64
#define NP_ 2060          // unique p positions per batch: t + 2k, t<2048, k<7
#define MSTRIDE 144       // floats per 12x12 matrix in global ws
#define LSTRIDE 148       // padded LDS stride for k3 (2-way max conflict = free)

// ------------------------------------------------------------------
// Quad-lane DPP broadcast: all 4 lanes of a quad get lane Q's value.
// ------------------------------------------------------------------
template <int Q>
__device__ __forceinline__ float qb(float v) {
  return __int_as_float(
      __builtin_amdgcn_mov_dpp(__float_as_int(v), Q * 0x55, 0xf, 0xf, true));
}

// C(3x12, own rows) = A(3x12, own rows) * B(12x12, quad-distributed rows)
__device__ __forceinline__ void qmm(const float a[3][12], const float b[3][12],
                                    float c[3][12]) {
#pragma unroll
  for (int i = 0; i < 3; ++i)
#pragma unroll
    for (int j = 0; j < 12; ++j) c[i][j] = 0.f;
#define QMM_K(OWNER, E)                                                  \
  {                                                                      \
    float bk[12];                                                        \
    _Pragma("unroll")                                                    \
    for (int j = 0; j < 12; ++j) bk[j] = qb<OWNER>(b[E][j]);             \
    _Pragma("unroll")                                                    \
    for (int i = 0; i < 3; ++i) {                                        \
      const float av = a[i][3 * OWNER + E];                              \
      _Pragma("unroll")                                                  \
      for (int j = 0; j < 12; ++j) c[i][j] = fmaf(av, bk[j], c[i][j]);   \
    }                                                                    \
  }
  QMM_K(0, 0) QMM_K(0, 1) QMM_K(0, 2)
  QMM_K(1, 0) QMM_K(1, 1) QMM_K(1, 2)
  QMM_K(2, 0) QMM_K(2, 1) QMM_K(2, 2)
  QMM_K(3, 0) QMM_K(3, 1) QMM_K(3, 2)
#undef QMM_K
}

// C(3x12, own rows) = A(3x12, own rows) * B(12x12 in LDS, rows contiguous)
// Quad-uniform addresses -> LDS broadcast, no DPP, no barrier (read-only B).
__device__ __forceinline__ void matmul_rows(const float a[3][12],
                                            const float* lb, float c[3][12]) {
#pragma unroll
  for (int i = 0; i < 3; ++i)
#pragma unroll
    for (int j = 0; j < 12; ++j) c[i][j] = 0.f;
#pragma unroll
  for (int k = 0; k < 12; ++k) {
    float4 b0 = *(const float4*)(lb + k * 12 + 0);
    float4 b1 = *(const float4*)(lb + k * 12 + 4);
    float4 b2 = *(const float4*)(lb + k * 12 + 8);
#pragma unroll
    for (int i = 0; i < 3; ++i) {
      const float a_ = a[i][k];
      c[i][0] += a_ * b0.x;  c[i][1] += a_ * b0.y;  c[i][2]  += a_ * b0.z;  c[i][3]  += a_ * b0.w;
      c[i][4] += a_ * b1.x;  c[i][5] += a_ * b1.y;  c[i][6]  += a_ * b1.z;  c[i][7]  += a_ * b1.w;
      c[i][8] += a_ * b2.x;  c[i][9] += a_ * b2.y;  c[i][10] += a_ * b2.z;  c[i][11] += a_ * b2.w;
    }
  }
}

// ------------------------------------------------------------------
// K12 (fused): build scaled M in registers, expm in registers, write E.
// M[b][p] = sum_c dx[p][c] * Ask[c] with Ask pre-scaled by 2^-5.
// expm: Paterson-Stockmeyer degree-6 Taylor (3 mults) + 5 squarings.
// One quad per matrix, 3 rows/lane, DPP broadcasts, no barriers after staging.
// ------------------------------------------------------------------
__global__ __launch_bounds__(256) void k12_build_expm(const float* __restrict__ x,
                                                      const float* __restrict__ A,
                                                      float* __restrict__ E) {
  __shared__ float ask[64][144];   // skew-symmetrized, pre-scaled A
  __shared__ float dx[64][65];
  const int b = blockIdx.y;
  const int p0 = blockIdx.x * 64;
  const int tid = threadIdx.x;

  const float sc = 1.0f / 32.0f;   // 2^-5 folded into Ask
  for (int i = tid; i < 64 * 144; i += 256) {
    int c = i / 144, e = i - c * 144;
    int h = e / 12, w = e - h * 12;
    ask[c][e] = (A[c * 144 + e] - A[c * 144 + w * 12 + h]) * sc;
  }
  for (int i = tid; i < 64 * 64; i += 256) {
    int pl = i >> 6, c = i & 63;
    int p = p0 + pl;
    float v = 0.f;
    if (p < NP_) {
      int i1 = min(max(p - 7, 0), T_ - 1);
      int i2 = min(max(p - 5, 0), T_ - 1);
      const float* xb = x + (size_t)b * T_ * C_;
      v = xb[(size_t)i2 * C_ + c] - xb[(size_t)i1 * C_ + c];
    }
    dx[pl][c] = v;
  }
  __syncthreads();

  const int eg = tid & 3;          // quad lane: owns rows 3*eg..3*eg+2
  const int nl = tid >> 2;         // matrix (p) within block
  const int p = p0 + nl;

  // ---- build scaled M rows (a = my 3 rows of M/32) ----
  float a[3][12];
  float* af = &a[0][0];
#pragma unroll
  for (int j = 0; j < 36; ++j) af[j] = 0.f;
  const int e0 = eg * 36;
  for (int c = 0; c < 64; ++c) {
    float d = dx[nl][c];
    const float4* ar = (const float4*)&ask[c][e0];
#pragma unroll
    for (int q = 0; q < 9; ++q) {
      float4 v = ar[q];
      af[q * 4 + 0] += d * v.x;
      af[q * 4 + 1] += d * v.y;
      af[q * 4 + 2] += d * v.z;
      af[q * 4 + 3] += d * v.w;
    }
  }

  // ---- expm via PS-6 + 5 squarings (8 matmuls total) ----
  float b2[3][12], d3[3][12], pp[3][12];
  qmm(a, a, b2);      // M2
  qmm(b2, a, d3);     // M3

  // pp = I + M + M2/2 + M3/6
#pragma unroll
  for (int i = 0; i < 3; ++i)
#pragma unroll
    for (int j = 0; j < 12; ++j)
      pp[i][j] = a[i][j] + b2[i][j] * 0.5f + d3[i][j] * (1.0f / 6.0f) +
                 ((j == 3 * eg + i) ? 1.0f : 0.0f);

  // w (into a) = M/24 + M2/120 + M3/720
#pragma unroll
  for (int i = 0; i < 3; ++i)
#pragma unroll
    for (int j = 0; j < 12; ++j)
      a[i][j] = a[i][j] * (1.0f / 24.0f) + b2[i][j] * (1.0f / 120.0f) +
                d3[i][j] * (1.0f / 720.0f);

  qmm(d3, a, b2);     // M3 * W  (yields M4/24 + M5/120 + M6/720)
#pragma unroll
  for (int i = 0; i < 3; ++i)
#pragma unroll
    for (int j = 0; j < 12; ++j) pp[i][j] += b2[i][j];

  // 5 squarings: result lands in b2
  qmm(pp, pp, b2);
  qmm(b2, b2, pp);
  qmm(pp, pp, b2);
  qmm(b2, b2, pp);
  qmm(pp, pp, b2);

  if (p < NP_) {
    float* gp = E + ((size_t)b * NP_ + p) * MSTRIDE + 36 * eg;
#pragma unroll
    for (int i = 0; i < 3; ++i)
#pragma unroll
      for (int q = 0; q < 3; ++q)
        *(float4*)(gp + i * 12 + q * 4) =
            make_float4(b2[i][q * 4 + 0], b2[i][q * 4 + 1],
                        b2[i][q * 4 + 2], b2[i][q * 4 + 3]);
  }
}

// ------------------------------------------------------------------
// K3: per window t: Z = E(t) * E(t+2) * ... * E(t+12); out = [Z(144), xp[t](64)]
// 64 windows/block; stage the 76 needed E's in LDS once; chain matmuls read B
// straight from LDS (quad-uniform broadcast reads, no barriers).
// ------------------------------------------------------------------
__global__ __launch_bounds__(256) void k3_chain(const float* __restrict__ E,
                                                const float* __restrict__ x,
                                                float* __restrict__ out) {
  __shared__ float eb[76][LSTRIDE];
  const int b = blockIdx.y;
  const int t0 = blockIdx.x * 64;
  const float* src = E + ((size_t)b * NP_ + t0) * MSTRIDE;
  for (int i = threadIdx.x; i < 76 * 36; i += 256) {
    int m = i / 36, q = i - m * 36;
    *(float4*)(&eb[m][q * 4]) = *(const float4*)(src + (size_t)m * MSTRIDE + q * 4);
  }
  __syncthreads();

  const int r = threadIdx.x & 3;
  const int tl = threadIdx.x >> 2;  // 0..63 window within block
  const int t = t0 + tl;

  float z[3][12], c[3][12];
#pragma unroll
  for (int i = 0; i < 3; ++i) {
    const float* zp = &eb[tl][(3 * r + i) * 12];
    float4 v0 = *(const float4*)(zp + 0);
    float4 v1 = *(const float4*)(zp + 4);
    float4 v2 = *(const float4*)(zp + 8);
    z[i][0] = v0.x; z[i][1] = v0.y; z[i][2]  = v0.z; z[i][3]  = v0.w;
    z[i][4] = v1.x; z[i][5] = v1.y; z[i][6]  = v1.z; z[i][7]  = v1.w;
    z[i][8] = v2.x; z[i][9] = v2.y; z[i][10] = v2.z; z[i][11] = v2.w;
  }
  matmul_rows(z, &eb[tl + 2][0], c);
  matmul_rows(c, &eb[tl + 4][0], z);
  matmul_rows(z, &eb[tl + 6][0], c);
  matmul_rows(c, &eb[tl + 8][0], z);
  matmul_rows(z, &eb[tl + 10][0], c);
  matmul_rows(c, &eb[tl + 12][0], z);

  const size_t obase = ((size_t)b * T_ + t) * 208;
#pragma unroll
  for (int i = 0; i < 3; ++i) {
    const int row = 3 * r + i;
    *(float4*)(out + obase + row * 12 + 0) = make_float4(z[i][0], z[i][1], z[i][2],  z[i][3]);
    *(float4*)(out + obase + row * 12 + 4) = make_float4(z[i][4], z[i][5], z[i][6],  z[i][7]);
    *(float4*)(out + obase + row * 12 + 8) = make_float4(z[i][8], z[i][9], z[i][10], z[i][11]);
  }
  const int xi = min(max(t - 7, 0), T_ - 1);
  const float* xr = x + ((size_t)b * T_ + xi) * C_ + 16 * r;
#pragma unroll
  for (int q = 0; q < 4; ++q) {
    *(float4*)(out + obase + 144 + 16 * r + q * 4) = *(const float4*)(xr + q * 4);
  }
}

// ------------------------------------------------------------------
extern "C" void kernel_launch(void* const* d_in, const int* in_sizes, int n_in,
                              void* d_out, int out_size, void* d_ws, size_t ws_size,
                              hipStream_t stream) {
  (void)in_sizes; (void)n_in; (void)out_size;
  const float* x = (const float*)d_in[0];
  const float* A = (const float*)d_in[1];
  float* out = (float*)d_out;
  float* E = (float*)d_ws;

  const size_t need = (size_t)B_ * NP_ * MSTRIDE * sizeof(float);  // ~38 MB
  if (ws_size < need) return;

  k12_build_expm<<<dim3(33, B_), 256, 0, stream>>>(x, A, E);
  k3_chain<<<dim3(T_ / 64, B_), 256, 0, stream>>>(E, x, out);
}